// Round 3
// baseline (1280.773 us; speedup 1.0000x reference)
//
#include <hip/hip_runtime.h>
#include <hip/hip_bf16.h>

typedef __bf16 bf16;
typedef __bf16 bf16x4 __attribute__((ext_vector_type(4)));
typedef __bf16 bf16x8 __attribute__((ext_vector_type(8)));
typedef float f32x4 __attribute__((ext_vector_type(4)));

#define T_TOK 4096
#define DDIM 1024
#define FDIM 4096
#define NEXP 8
#define NSLOT (2 * T_TOK)          // 8192 expert-slots
#define HROWS (NSLOT + 128)        // slack for tail-tile overreads

// async global->LDS, 16B per lane; LDS dest must be wave-uniform base,
// data lands at base + lane*16 (m97/m104 semantics)
__device__ __forceinline__ void async_copy16(const void* g, void* l) {
    __builtin_amdgcn_global_load_lds(
        (const __attribute__((address_space(1))) void*)g,
        (__attribute__((address_space(3))) void*)l, 16, 0, 0);
}

// ---------------- cast fp32 -> bf16 (x) -----------------------------------
__global__ __launch_bounds__(256) void k_cast(
    const float* __restrict__ in, bf16* __restrict__ out, int n4)
{
    int i = blockIdx.x * 256 + threadIdx.x;
    if (i >= n4) return;
    float4 v = ((const float4*)in)[i];
    bf16x4 o;
    o[0] = (bf16)v.x; o[1] = (bf16)v.y; o[2] = (bf16)v.z; o[3] = (bf16)v.w;
    ((bf16x4*)out)[i] = o;
}

// ---------------- router: fp32 logits, softmax top-2, counts, rl ----------
__global__ __launch_bounds__(256) void k_router(
    const float* __restrict__ x, const float* __restrict__ gw,
    float* __restrict__ out_rl, int* __restrict__ topE, float* __restrict__ topW,
    int* __restrict__ cnt)
{
    int wid = threadIdx.x >> 6, lane = threadIdx.x & 63;
    int t = blockIdx.x * 4 + wid;
    const float4* xr = (const float4*)(x + (size_t)t * DDIM);
    const float4* gr = (const float4*)gw;
    float acc[NEXP];
#pragma unroll
    for (int e = 0; e < NEXP; ++e) acc[e] = 0.f;
#pragma unroll
    for (int i = 0; i < 4; ++i) {
        float4 xv = xr[lane + 64 * i];
#pragma unroll
        for (int e = 0; e < NEXP; ++e) {
            float4 gv = gr[e * 256 + lane + 64 * i];
            acc[e] += xv.x * gv.x + xv.y * gv.y + xv.z * gv.z + xv.w * gv.w;
        }
    }
#pragma unroll
    for (int e = 0; e < NEXP; ++e) {
#pragma unroll
        for (int s = 32; s > 0; s >>= 1) acc[e] += __shfl_down(acc[e], s, 64);
    }
    if (lane == 0) {
        float mx = acc[0];
#pragma unroll
        for (int e = 1; e < NEXP; ++e) mx = fmaxf(mx, acc[e]);
        float p[NEXP];
#pragma unroll
        for (int e = 0; e < NEXP; ++e) p[e] = __expf(acc[e] - mx);
        int e0 = 0;
#pragma unroll
        for (int e = 1; e < NEXP; ++e) if (p[e] > p[e0]) e0 = e;
        int e1 = (e0 == 0) ? 1 : 0;
#pragma unroll
        for (int e = 0; e < NEXP; ++e) if (e != e0 && p[e] > p[e1]) e1 = e;
        float s = p[e0] + p[e1];
        topE[2 * t] = e0; topE[2 * t + 1] = e1;
        topW[2 * t] = p[e0] / s; topW[2 * t + 1] = p[e1] / s;
        atomicAdd(&cnt[e0], 1); atomicAdd(&cnt[e1], 1);
        int b = t >> 10;
#pragma unroll
        for (int e = 0; e < NEXP; ++e)
            atomicAdd(&out_rl[b * NEXP + e], acc[e] * (1.f / 1024.f));
    }
}

// ---------------- tiny exclusive scan over 8 experts ----------------------
__global__ void k_scan(const int* __restrict__ cnt, int* __restrict__ offs,
                       int* __restrict__ fill)
{
    if (threadIdx.x == 0) {
        int s = 0;
        for (int e = 0; e < NEXP; ++e) { offs[e] = s; s += cnt[e]; }
    }
    if (threadIdx.x < NEXP) fill[threadIdx.x] = 0;
}

// ---------------- build per-expert token lists + inverse ------------------
__global__ __launch_bounds__(256) void k_build(
    const int* __restrict__ topE, const float* __restrict__ topW,
    const int* __restrict__ offs, int* __restrict__ fill,
    int* __restrict__ list, float* __restrict__ wlist, int* __restrict__ inv)
{
    int t = blockIdx.x * blockDim.x + threadIdx.x;
    if (t >= T_TOK) return;
#pragma unroll
    for (int k = 0; k < 2; ++k) {
        int e = topE[2 * t + k];
        int p = atomicAdd(&fill[e], 1);
        int s = offs[e] + p;
        list[s] = t;
        wlist[s] = topW[2 * t + k];
        inv[2 * t + k] = s;
    }
}

// ------ weight transpose+cast [E][R][C] fp32 -> [E][C][R] bf16, 64x64 -----
__global__ __launch_bounds__(256) void k_tc64(
    const float* __restrict__ in, bf16* __restrict__ out, int R, int C)
{
    __shared__ float tile[64][72];
    int e = blockIdx.z;
    const float* I = in + (size_t)e * R * C;
    bf16* O = out + (size_t)e * R * C;
    int c0 = blockIdx.x * 64, r0 = blockIdx.y * 64;
    int tid = threadIdx.x;
#pragma unroll
    for (int it = 0; it < 4; ++it) {
        int idx = it * 256 + tid;              // 1024 float4 slots
        int row = idx >> 4, c4 = idx & 15;
        float4 v = *(const float4*)(I + (size_t)(r0 + row) * C + c0 + c4 * 4);
        tile[row][c4 * 4 + 0] = v.x; tile[row][c4 * 4 + 1] = v.y;
        tile[row][c4 * 4 + 2] = v.z; tile[row][c4 * 4 + 3] = v.w;
    }
    __syncthreads();
#pragma unroll
    for (int it = 0; it < 4; ++it) {
        int idx = it * 256 + tid;
        int c = idx >> 4, r4 = idx & 15;
        bf16x4 o;
#pragma unroll
        for (int j = 0; j < 4; ++j) o[j] = (bf16)tile[r4 * 4 + j][c];
        *(bf16x4*)(O + (size_t)(c0 + c) * R + r0 + r4 * 4) = o;
    }
}

// ------ fused GEMM1: H = silu(Xg@w1t) * (Xg@w3t) * w_slot -----------------
// 128x128x32 tile, double-buffered async staging: prefetch tile k+1 is
// issued BEFORE computing tile k, so the vmcnt(0) drain at the barrier
// lands after a full MFMA phase (latency hidden). Flat 1-D LDS, literal
// buffer offsets (B*4096), no lambdas. XOR-swizzled (seg ^= (row>>1)&3).
__global__ __launch_bounds__(256) void k_gemm01(
    const bf16* __restrict__ xb, const bf16* __restrict__ B1w,
    const bf16* __restrict__ B3w, bf16* __restrict__ Hbuf,
    const int* __restrict__ cnt, const int* __restrict__ offs,
    const int* __restrict__ list, const float* __restrict__ wlist)
{
    const int e = blockIdx.z, mt = blockIdx.y, nt = blockIdx.x;
    const int count = cnt[e];
    if (mt * 128 >= count) return;
    const int off = offs[e];
    const int tid = threadIdx.x;
    const int lane = tid & 63;
    const int wid = tid >> 6;
    const int wm = (wid >> 1) * 64, wn = (wid & 1) * 64;
    const int lr = lane & 15, segn = lane >> 4;

    __shared__ __attribute__((aligned(16))) bf16 As[2 * 128 * 32];
    __shared__ __attribute__((aligned(16))) bf16 B1s[2 * 128 * 32];
    __shared__ __attribute__((aligned(16))) bf16 B3s[2 * 128 * 32];
    __shared__ int tokbuf[128];

    if (tid < 128) {
        int p = mt * 128 + tid;
        int t = (p < count) ? list[off + p] : 0;   // clamp: garbage rows skipped in epilogue
        tokbuf[tid] = t;
    }
    __syncthreads();

    // staging geometry: lane data lands at LDS elems (B*4096 + it*2048 + tid*8)
    const int srow = tid >> 2;                      // + it*64
    const int gseg = (tid & 3) ^ ((srow >> 1) & 3); // same for it=0/1 (row+64 keeps (row>>1)&3)
    const int ldsw = wid * 512;                     // wave-uniform base (elems), + it*2048
    const size_t acol = (size_t)gseg * 8;

    // fragment LDS offsets (constant across k-steps)
    int aoff[4], boff[4];
#pragma unroll
    for (int i = 0; i < 4; ++i) {
        int ra = wm + i * 16 + lr;
        aoff[i] = ra * 32 + ((((ra >> 1) & 3) ^ segn)) * 8;
        int rb = wn + i * 16 + lr;
        boff[i] = rb * 32 + ((((rb >> 1) & 3) ^ segn)) * 8;
    }

    f32x4 acc1[4][4], acc3[4][4];
#pragma unroll
    for (int i = 0; i < 4; ++i)
#pragma unroll
        for (int j = 0; j < 4; ++j)
#pragma unroll
            for (int r = 0; r < 4; ++r) { acc1[i][j][r] = 0.f; acc3[i][j][r] = 0.f; }

    const bf16* B1base = B1w + ((size_t)e * FDIM + (size_t)nt * 128) * DDIM;
    const bf16* B3base = B3w + ((size_t)e * FDIM + (size_t)nt * 128) * DDIM;
    const int trow0 = tokbuf[srow], trow1 = tokbuf[srow + 64];

#define STAGE01(B, KK)                                                          \
    {                                                                           \
        size_t col_ = (size_t)(KK) + acol;                                      \
        async_copy16(xb + (size_t)trow0 * DDIM + col_,                          \
                     As + (B) * 4096 + ldsw);                                   \
        async_copy16(B1base + (size_t)srow * DDIM + col_,                       \
                     B1s + (B) * 4096 + ldsw);                                  \
        async_copy16(B3base + (size_t)srow * DDIM + col_,                       \
                     B3s + (B) * 4096 + ldsw);                                  \
        async_copy16(xb + (size_t)trow1 * DDIM + col_,                          \
                     As + (B) * 4096 + 2048 + ldsw);                            \
        async_copy16(B1base + (size_t)(srow + 64) * DDIM + col_,                \
                     B1s + (B) * 4096 + 2048 + ldsw);                           \
        async_copy16(B3base + (size_t)(srow + 64) * DDIM + col_,                \
                     B3s + (B) * 4096 + 2048 + ldsw);                           \
    }

#define COMP01(B)                                                               \
    {                                                                           \
        bf16x8 af[4], b1f[4], b3f[4];                                           \
        _Pragma("unroll")                                                       \
        for (int i = 0; i < 4; ++i) {                                           \
            af[i]  = *(const bf16x8*)(As + (B) * 4096 + aoff[i]);               \
            b1f[i] = *(const bf16x8*)(B1s + (B) * 4096 + boff[i]);              \
            b3f[i] = *(const bf16x8*)(B3s + (B) * 4096 + boff[i]);              \
        }                                                                       \
        _Pragma("unroll")                                                       \
        for (int i = 0; i < 4; ++i)                                             \
            _Pragma("unroll")                                                   \
            for (int j = 0; j < 4; ++j) {                                       \
                acc1[i][j] = __builtin_amdgcn_mfma_f32_16x16x32_bf16(           \
                    af[i], b1f[j], acc1[i][j], 0, 0, 0);                        \
                acc3[i][j] = __builtin_amdgcn_mfma_f32_16x16x32_bf16(           \
                    af[i], b3f[j], acc3[i][j], 0, 0, 0);                        \
            }                                                                   \
    }

    STAGE01(0, 0)
    __syncthreads();                     // vmcnt(0) drain: tile 0 resident
    for (int kk = 0; kk < DDIM; kk += 64) {
        STAGE01(1, kk + 32)              // prefetch next tile (in flight under MFMA)
        COMP01(0)
        __syncthreads();                 // drain lands AFTER compute
        if (kk + 64 < DDIM) STAGE01(0, kk + 64)
        COMP01(1)
        __syncthreads();
    }
#undef STAGE01
#undef COMP01

    // C/D layout: col = lane&15, row = (lane>>4)*4 + reg
    const int lcol = lane & 15, lrow0 = (lane >> 4) * 4;
#pragma unroll
    for (int i = 0; i < 4; ++i) {
#pragma unroll
        for (int r = 0; r < 4; ++r) {
            int p = mt * 128 + wm + i * 16 + lrow0 + r;
            if (p >= count) continue;
            int slot = off + p;
            float wl = wlist[slot];
#pragma unroll
            for (int j = 0; j < 4; ++j) {
                int n = nt * 128 + wn + j * 16 + lcol;
                float a = acc1[i][j][r];
                float sv = a / (1.f + __expf(-a));
                Hbuf[(size_t)slot * FDIM + n] = (bf16)(sv * acc3[i][j][r] * wl);
            }
        }
    }
}

// ------ GEMM2: ObufS[kslice][slot] = H @ w2t (split-K=2, no atomics) ------
// same double-buffered prefetch structure as k_gemm01
__global__ __launch_bounds__(256) void k_gemm2(
    const bf16* __restrict__ Hbuf, const bf16* __restrict__ B2w,
    float* __restrict__ ObufS,
    const int* __restrict__ cnt, const int* __restrict__ offs)
{
    const int kslice = blockIdx.z >> 3, e = blockIdx.z & 7;
    const int mt = blockIdx.y, nt = blockIdx.x;
    const int count = cnt[e];
    if (mt * 128 >= count) return;
    const int off = offs[e];
    const int tid = threadIdx.x;
    const int lane = tid & 63;
    const int wid = tid >> 6;
    const int wm = (wid >> 1) * 64, wn = (wid & 1) * 64;
    const int lr = lane & 15, segn = lane >> 4;

    __shared__ __attribute__((aligned(16))) bf16 As[2 * 128 * 32];
    __shared__ __attribute__((aligned(16))) bf16 Bs[2 * 128 * 32];

    const int srow = tid >> 2;
    const int gseg = (tid & 3) ^ ((srow >> 1) & 3);
    const int ldsw = wid * 512;
    const size_t acol = (size_t)gseg * 8;

    int aoff[4], boff[4];
#pragma unroll
    for (int i = 0; i < 4; ++i) {
        int ra = wm + i * 16 + lr;
        aoff[i] = ra * 32 + ((((ra >> 1) & 3) ^ segn)) * 8;
        int rb = wn + i * 16 + lr;
        boff[i] = rb * 32 + ((((rb >> 1) & 3) ^ segn)) * 8;
    }

    f32x4 acc[4][4];
#pragma unroll
    for (int i = 0; i < 4; ++i)
#pragma unroll
        for (int j = 0; j < 4; ++j)
#pragma unroll
            for (int r = 0; r < 4; ++r) acc[i][j][r] = 0.f;

    const bf16* Abase = Hbuf + (size_t)(off + mt * 128) * FDIM;  // HROWS slack covers tail
    const bf16* Bbase = B2w + ((size_t)e * DDIM + (size_t)nt * 128) * FDIM;
    const int k0 = kslice * (FDIM / 2), k1 = k0 + FDIM / 2;

#define STAGE2(B, KK)                                                           \
    {                                                                           \
        size_t col_ = (size_t)(KK) + acol;                                      \
        async_copy16(Abase + (size_t)srow * FDIM + col_,                        \
                     As + (B) * 4096 + ldsw);                                   \
        async_copy16(Bbase + (size_t)srow * FDIM + col_,                        \
                     Bs + (B) * 4096 + ldsw);                                   \
        async_copy16(Abase + (size_t)(srow + 64) * FDIM + col_,                 \
                     As + (B) * 4096 + 2048 + ldsw);                            \
        async_copy16(Bbase + (size_t)(srow + 64) * FDIM + col_,                 \
                     Bs + (B) * 4096 + 2048 + ldsw);                            \
    }

#define COMP2(B)                                                                \
    {                                                                           \
        bf16x8 af[4], bfr[4];                                                   \
        _Pragma("unroll")                                                       \
        for (int i = 0; i < 4; ++i) {                                           \
            af[i]  = *(const bf16x8*)(As + (B) * 4096 + aoff[i]);               \
            bfr[i] = *(const bf16x8*)(Bs + (B) * 4096 + boff[i]);               \
        }                                                                       \
        _Pragma("unroll")                                                       \
        for (int i = 0; i < 4; ++i)                                             \
            _Pragma("unroll")                                                   \
            for (int j = 0; j < 4; ++j)                                         \
                acc[i][j] = __builtin_amdgcn_mfma_f32_16x16x32_bf16(            \
                    af[i], bfr[j], acc[i][j], 0, 0, 0);                         \
    }

    STAGE2(0, k0)
    __syncthreads();
    for (int kk = k0; kk < k1; kk += 64) {
        STAGE2(1, kk + 32)
        COMP2(0)
        __syncthreads();
        if (kk + 64 < k1) STAGE2(0, kk + 64)
        COMP2(1)
        __syncthreads();
    }
#undef STAGE2
#undef COMP2

    const int lcol = lane & 15, lrow0 = (lane >> 4) * 4;
    float* Oslice = ObufS + (size_t)kslice * NSLOT * DDIM;
#pragma unroll
    for (int i = 0; i < 4; ++i) {
#pragma unroll
        for (int r = 0; r < 4; ++r) {
            int p = mt * 128 + wm + i * 16 + lrow0 + r;
            if (p >= count) continue;
            float* orow = Oslice + (size_t)(off + p) * DDIM + nt * 128 + wn + lcol;
#pragma unroll
            for (int j = 0; j < 4; ++j) orow[j * 16] = acc[i][j][r];
        }
    }
}

// ------ combine: out[t] = sum over 2 slots x 2 kslices --------------------
__global__ __launch_bounds__(256) void k_combine(
    const float* __restrict__ ObufS, const int* __restrict__ inv,
    float* __restrict__ out)
{
    int i = blockIdx.x * 256 + threadIdx.x;   // T*D/4 float4 units
    int t = i >> 8, d4 = i & 255;             // D/4 = 256
    int s0 = inv[2 * t], s1 = inv[2 * t + 1];
    const float4* O = (const float4*)ObufS;
    float4 a = O[(size_t)s0 * 256 + d4];
    float4 b = O[(size_t)s1 * 256 + d4];
    float4 c = O[(size_t)(NSLOT + s0) * 256 + d4];
    float4 d = O[(size_t)(NSLOT + s1) * 256 + d4];
    float4 r;
    r.x = a.x + b.x + c.x + d.x;
    r.y = a.y + b.y + c.y + d.y;
    r.z = a.z + b.z + c.z + d.z;
    r.w = a.w + b.w + c.w + d.w;
    ((float4*)out)[i] = r;
}

extern "C" void kernel_launch(void* const* d_in, const int* in_sizes, int n_in,
                              void* d_out, int out_size, void* d_ws, size_t ws_size,
                              hipStream_t stream)
{
    const float* x  = (const float*)d_in[0];
    const float* gw = (const float*)d_in[1];
    const float* w1 = (const float*)d_in[2];
    const float* w3 = (const float*)d_in[3];
    const float* w2 = (const float*)d_in[4];
    float* out = (float*)d_out;

    char* ws = (char*)d_ws;
    size_t o = 0;
    auto alloc = [&](size_t bytes) {
        char* p = ws + o;
        o += (bytes + 255) & ~(size_t)255;
        return p;
    };
    const size_t wsz = (size_t)NEXP * DDIM * FDIM * sizeof(bf16);   // 64 MiB
    bf16*  w1t   = (bf16*)alloc(wsz);                        // later: w2t
    bf16*  w3t   = (bf16*)alloc(wsz);                        // later: ObufS (fp32, exactly 64 MiB)
    bf16*  Hbuf  = (bf16*)alloc((size_t)HROWS * FDIM * sizeof(bf16));
    bf16*  xb    = (bf16*)alloc((size_t)T_TOK * DDIM * sizeof(bf16));
    int*   topE  = (int*)alloc(T_TOK * 2 * sizeof(int));
    float* topW  = (float*)alloc(T_TOK * 2 * sizeof(float));
    int*   cnt   = (int*)alloc(NEXP * sizeof(int));
    int*   offs  = (int*)alloc(NEXP * sizeof(int));
    int*   fill  = (int*)alloc(NEXP * sizeof(int));
    int*   list  = (int*)alloc(NSLOT * sizeof(int));
    float* wlist = (float*)alloc(NSLOT * sizeof(float));
    int*   inv   = (int*)alloc(NSLOT * sizeof(int));
    bf16*  w2t   = w1t;                   // after gemm01, w1t region is free
    float* ObufS = (float*)w3t;           // after gemm01, w3t region is free (2*NSLOT*DDIM*4 = 64 MiB)

    hipMemsetAsync(out, 0, (size_t)out_size * sizeof(float), stream);
    hipMemsetAsync(cnt, 0, NEXP * sizeof(int), stream);

    float* out_rl = out + (size_t)T_TOK * DDIM;

    k_cast<<<T_TOK * DDIM / 4 / 256, 256, 0, stream>>>(x, xb, T_TOK * DDIM / 4);
    k_router<<<T_TOK / 4, 256, 0, stream>>>(x, gw, out_rl, topE, topW, cnt);
    k_scan<<<1, 64, 0, stream>>>(cnt, offs, fill);
    k_build<<<(T_TOK + 255) / 256, 256, 0, stream>>>(topE, topW, offs, fill, list, wlist, inv);

    k_tc64<<<dim3(FDIM / 64, DDIM / 64, NEXP), 256, 0, stream>>>(w1, w1t, DDIM, FDIM);
    k_tc64<<<dim3(FDIM / 64, DDIM / 64, NEXP), 256, 0, stream>>>(w3, w3t, DDIM, FDIM);

    k_gemm01<<<dim3(FDIM / 128, T_TOK / 128, NEXP), 256, 0, stream>>>(
        xb, w1t, w3t, Hbuf, cnt, offs, list, wlist);

    k_tc64<<<dim3(DDIM / 64, FDIM / 64, NEXP), 256, 0, stream>>>(w2, w2t, FDIM, DDIM);

    k_gemm2<<<dim3(DDIM / 128, T_TOK / 128, NEXP * 2), 256, 0, stream>>>(
        Hbuf, w2t, ObufS, cnt, offs);

    k_combine<<<T_TOK * DDIM / 4 / 256, 256, 0, stream>>>(ObufS, inv, out);
}

// Round 4
// 1149.225 us; speedup vs baseline: 1.1145x; 1.1145x over previous
//
#include <hip/hip_runtime.h>
#include <hip/hip_bf16.h>

typedef __bf16 bf16;
typedef __bf16 bf16x4 __attribute__((ext_vector_type(4)));
typedef __bf16 bf16x8 __attribute__((ext_vector_type(8)));
typedef float f32x4 __attribute__((ext_vector_type(4)));

#define T_TOK 4096
#define DDIM 1024
#define FDIM 4096
#define NEXP 8
#define NSLOT (2 * T_TOK)          // 8192 expert-slots
#define HROWS (NSLOT + 128)        // slack for tail-tile overreads

// async global->LDS, 16B per lane; LDS dest must be wave-uniform base,
// data lands at base + lane*16 (m97/m104 semantics)
__device__ __forceinline__ void async_copy16(const void* g, void* l) {
    __builtin_amdgcn_global_load_lds(
        (const __attribute__((address_space(1))) void*)g,
        (__attribute__((address_space(3))) void*)l, 16, 0, 0);
}

// ---------------- cast fp32 -> bf16 (x) -----------------------------------
__global__ __launch_bounds__(256) void k_cast(
    const float* __restrict__ in, bf16* __restrict__ out, int n4)
{
    int i = blockIdx.x * 256 + threadIdx.x;
    if (i >= n4) return;
    float4 v = ((const float4*)in)[i];
    bf16x4 o;
    o[0] = (bf16)v.x; o[1] = (bf16)v.y; o[2] = (bf16)v.z; o[3] = (bf16)v.w;
    ((bf16x4*)out)[i] = o;
}

// ---------------- router: fp32 logits, softmax top-2, counts, rl ----------
__global__ __launch_bounds__(256) void k_router(
    const float* __restrict__ x, const float* __restrict__ gw,
    float* __restrict__ out_rl, int* __restrict__ topE, float* __restrict__ topW,
    int* __restrict__ cnt)
{
    int wid = threadIdx.x >> 6, lane = threadIdx.x & 63;
    int t = blockIdx.x * 4 + wid;
    const float4* xr = (const float4*)(x + (size_t)t * DDIM);
    const float4* gr = (const float4*)gw;
    float acc[NEXP];
#pragma unroll
    for (int e = 0; e < NEXP; ++e) acc[e] = 0.f;
#pragma unroll
    for (int i = 0; i < 4; ++i) {
        float4 xv = xr[lane + 64 * i];
#pragma unroll
        for (int e = 0; e < NEXP; ++e) {
            float4 gv = gr[e * 256 + lane + 64 * i];
            acc[e] += xv.x * gv.x + xv.y * gv.y + xv.z * gv.z + xv.w * gv.w;
        }
    }
#pragma unroll
    for (int e = 0; e < NEXP; ++e) {
#pragma unroll
        for (int s = 32; s > 0; s >>= 1) acc[e] += __shfl_down(acc[e], s, 64);
    }
    if (lane == 0) {
        float mx = acc[0];
#pragma unroll
        for (int e = 1; e < NEXP; ++e) mx = fmaxf(mx, acc[e]);
        float p[NEXP];
#pragma unroll
        for (int e = 0; e < NEXP; ++e) p[e] = __expf(acc[e] - mx);
        int e0 = 0;
#pragma unroll
        for (int e = 1; e < NEXP; ++e) if (p[e] > p[e0]) e0 = e;
        int e1 = (e0 == 0) ? 1 : 0;
#pragma unroll
        for (int e = 0; e < NEXP; ++e) if (e != e0 && p[e] > p[e1]) e1 = e;
        float s = p[e0] + p[e1];
        topE[2 * t] = e0; topE[2 * t + 1] = e1;
        topW[2 * t] = p[e0] / s; topW[2 * t + 1] = p[e1] / s;
        atomicAdd(&cnt[e0], 1); atomicAdd(&cnt[e1], 1);
        int b = t >> 10;
#pragma unroll
        for (int e = 0; e < NEXP; ++e)
            atomicAdd(&out_rl[b * NEXP + e], acc[e] * (1.f / 1024.f));
    }
}

// ---------------- tiny exclusive scan over 8 experts ----------------------
__global__ void k_scan(const int* __restrict__ cnt, int* __restrict__ offs,
                       int* __restrict__ fill)
{
    if (threadIdx.x == 0) {
        int s = 0;
        for (int e = 0; e < NEXP; ++e) { offs[e] = s; s += cnt[e]; }
    }
    if (threadIdx.x < NEXP) fill[threadIdx.x] = 0;
}

// ---------------- build per-expert token lists + inverse ------------------
__global__ __launch_bounds__(256) void k_build(
    const int* __restrict__ topE, const float* __restrict__ topW,
    const int* __restrict__ offs, int* __restrict__ fill,
    int* __restrict__ list, float* __restrict__ wlist, int* __restrict__ inv)
{
    int t = blockIdx.x * blockDim.x + threadIdx.x;
    if (t >= T_TOK) return;
#pragma unroll
    for (int k = 0; k < 2; ++k) {
        int e = topE[2 * t + k];
        int p = atomicAdd(&fill[e], 1);
        int s = offs[e] + p;
        list[s] = t;
        wlist[s] = topW[2 * t + k];
        inv[2 * t + k] = s;
    }
}

// ------ weight transpose+cast [E][R][C] fp32 -> [E][C][R] bf16, 64x64 -----
__global__ __launch_bounds__(256) void k_tc64(
    const float* __restrict__ in, bf16* __restrict__ out, int R, int C)
{
    __shared__ float tile[64][72];
    int e = blockIdx.z;
    const float* I = in + (size_t)e * R * C;
    bf16* O = out + (size_t)e * R * C;
    int c0 = blockIdx.x * 64, r0 = blockIdx.y * 64;
    int tid = threadIdx.x;
#pragma unroll
    for (int it = 0; it < 4; ++it) {
        int idx = it * 256 + tid;              // 1024 float4 slots
        int row = idx >> 4, c4 = idx & 15;
        float4 v = *(const float4*)(I + (size_t)(r0 + row) * C + c0 + c4 * 4);
        tile[row][c4 * 4 + 0] = v.x; tile[row][c4 * 4 + 1] = v.y;
        tile[row][c4 * 4 + 2] = v.z; tile[row][c4 * 4 + 3] = v.w;
    }
    __syncthreads();
#pragma unroll
    for (int it = 0; it < 4; ++it) {
        int idx = it * 256 + tid;
        int c = idx >> 4, r4 = idx & 15;
        bf16x4 o;
#pragma unroll
        for (int j = 0; j < 4; ++j) o[j] = (bf16)tile[r4 * 4 + j][c];
        *(bf16x4*)(O + (size_t)(c0 + c) * R + r0 + r4 * 4) = o;
    }
}

// ------ fused GEMM1: H = silu(Xg@w1t) * (Xg@w3t) * w_slot -----------------
// 128x128x32 tile, double-buffered async staging.
// __launch_bounds__(256, 2): dual accumulators (acc1+acc3 = 128 regs) put
// unconstrained total at ~276 regs -> 1 wave/SIMD -> 1 block/CU -> no
// inter-block overlap (measured Occupancy 11%, MfmaUtil 16%). Forcing
// <=256 total gives 2 blocks/CU. Per-j B-fragment loads shrink live range.
__global__ __launch_bounds__(256, 2) void k_gemm01(
    const bf16* __restrict__ xb, const bf16* __restrict__ B1w,
    const bf16* __restrict__ B3w, bf16* __restrict__ Hbuf,
    const int* __restrict__ cnt, const int* __restrict__ offs,
    const int* __restrict__ list, const float* __restrict__ wlist)
{
    const int e = blockIdx.z, mt = blockIdx.y, nt = blockIdx.x;
    const int count = cnt[e];
    if (mt * 128 >= count) return;
    const int off = offs[e];
    const int tid = threadIdx.x;
    const int lane = tid & 63;
    const int wid = tid >> 6;
    const int wm = (wid >> 1) * 64, wn = (wid & 1) * 64;
    const int lr = lane & 15, segn = lane >> 4;

    __shared__ __attribute__((aligned(16))) bf16 As[2 * 128 * 32];
    __shared__ __attribute__((aligned(16))) bf16 B1s[2 * 128 * 32];
    __shared__ __attribute__((aligned(16))) bf16 B3s[2 * 128 * 32];
    __shared__ int tokbuf[128];

    if (tid < 128) {
        int p = mt * 128 + tid;
        int t = (p < count) ? list[off + p] : 0;   // clamp: garbage rows skipped in epilogue
        tokbuf[tid] = t;
    }
    __syncthreads();

    // staging geometry: lane data lands at LDS elems (B*4096 + it*2048 + tid*8)
    const int srow = tid >> 2;                      // + it*64
    const int gseg = (tid & 3) ^ ((srow >> 1) & 3); // same for it=0/1 (row+64 keeps (row>>1)&3)
    const int ldsw = wid * 512;                     // wave-uniform base (elems), + it*2048
    const size_t acol = (size_t)gseg * 8;

    // fragment LDS offsets (constant across k-steps)
    int aoff[4], boff[4];
#pragma unroll
    for (int i = 0; i < 4; ++i) {
        int ra = wm + i * 16 + lr;
        aoff[i] = ra * 32 + ((((ra >> 1) & 3) ^ segn)) * 8;
        int rb = wn + i * 16 + lr;
        boff[i] = rb * 32 + ((((rb >> 1) & 3) ^ segn)) * 8;
    }

    f32x4 acc1[4][4], acc3[4][4];
#pragma unroll
    for (int i = 0; i < 4; ++i)
#pragma unroll
        for (int j = 0; j < 4; ++j)
#pragma unroll
            for (int r = 0; r < 4; ++r) { acc1[i][j][r] = 0.f; acc3[i][j][r] = 0.f; }

    const bf16* B1base = B1w + ((size_t)e * FDIM + (size_t)nt * 128) * DDIM;
    const bf16* B3base = B3w + ((size_t)e * FDIM + (size_t)nt * 128) * DDIM;
    const int trow0 = tokbuf[srow], trow1 = tokbuf[srow + 64];

#define STAGE01(B, KK)                                                          \
    {                                                                           \
        size_t col_ = (size_t)(KK) + acol;                                      \
        async_copy16(xb + (size_t)trow0 * DDIM + col_,                          \
                     As + (B) * 4096 + ldsw);                                   \
        async_copy16(B1base + (size_t)srow * DDIM + col_,                       \
                     B1s + (B) * 4096 + ldsw);                                  \
        async_copy16(B3base + (size_t)srow * DDIM + col_,                       \
                     B3s + (B) * 4096 + ldsw);                                  \
        async_copy16(xb + (size_t)trow1 * DDIM + col_,                          \
                     As + (B) * 4096 + 2048 + ldsw);                            \
        async_copy16(B1base + (size_t)(srow + 64) * DDIM + col_,                \
                     B1s + (B) * 4096 + 2048 + ldsw);                           \
        async_copy16(B3base + (size_t)(srow + 64) * DDIM + col_,                \
                     B3s + (B) * 4096 + 2048 + ldsw);                           \
    }

// per-j B-fragment loads: only af[4] (16 regs) + b1j/b3j (8 regs) live,
// instead of 48 live fragment regs -> fits the (256,2) budget w/o spills
#define COMP01(B)                                                               \
    {                                                                           \
        bf16x8 af[4];                                                           \
        _Pragma("unroll")                                                       \
        for (int i = 0; i < 4; ++i)                                             \
            af[i] = *(const bf16x8*)(As + (B) * 4096 + aoff[i]);                \
        _Pragma("unroll")                                                       \
        for (int j = 0; j < 4; ++j) {                                           \
            bf16x8 b1j = *(const bf16x8*)(B1s + (B) * 4096 + boff[j]);          \
            bf16x8 b3j = *(const bf16x8*)(B3s + (B) * 4096 + boff[j]);          \
            _Pragma("unroll")                                                   \
            for (int i = 0; i < 4; ++i) {                                       \
                acc1[i][j] = __builtin_amdgcn_mfma_f32_16x16x32_bf16(           \
                    af[i], b1j, acc1[i][j], 0, 0, 0);                           \
                acc3[i][j] = __builtin_amdgcn_mfma_f32_16x16x32_bf16(           \
                    af[i], b3j, acc3[i][j], 0, 0, 0);                           \
            }                                                                   \
        }                                                                       \
    }

    STAGE01(0, 0)
    __syncthreads();                     // vmcnt(0) drain: tile 0 resident
    for (int kk = 0; kk < DDIM; kk += 64) {
        STAGE01(1, kk + 32)              // prefetch next tile (in flight under MFMA)
        COMP01(0)
        __syncthreads();                 // drain lands AFTER compute
        if (kk + 64 < DDIM) STAGE01(0, kk + 64)
        COMP01(1)
        __syncthreads();
    }
#undef STAGE01
#undef COMP01

    // C/D layout: col = lane&15, row = (lane>>4)*4 + reg
    const int lcol = lane & 15, lrow0 = (lane >> 4) * 4;
#pragma unroll
    for (int i = 0; i < 4; ++i) {
#pragma unroll
        for (int r = 0; r < 4; ++r) {
            int p = mt * 128 + wm + i * 16 + lrow0 + r;
            if (p >= count) continue;
            int slot = off + p;
            float wl = wlist[slot];
#pragma unroll
            for (int j = 0; j < 4; ++j) {
                int n = nt * 128 + wn + j * 16 + lcol;
                float a = acc1[i][j][r];
                float sv = a / (1.f + __expf(-a));
                Hbuf[(size_t)slot * FDIM + n] = (bf16)(sv * acc3[i][j][r] * wl);
            }
        }
    }
}

// ------ GEMM2: ObufS[kslice][slot] = H @ w2t (split-K=2, no atomics) ------
// same double-buffered prefetch structure as k_gemm01
__global__ __launch_bounds__(256, 2) void k_gemm2(
    const bf16* __restrict__ Hbuf, const bf16* __restrict__ B2w,
    float* __restrict__ ObufS,
    const int* __restrict__ cnt, const int* __restrict__ offs)
{
    const int kslice = blockIdx.z >> 3, e = blockIdx.z & 7;
    const int mt = blockIdx.y, nt = blockIdx.x;
    const int count = cnt[e];
    if (mt * 128 >= count) return;
    const int off = offs[e];
    const int tid = threadIdx.x;
    const int lane = tid & 63;
    const int wid = tid >> 6;
    const int wm = (wid >> 1) * 64, wn = (wid & 1) * 64;
    const int lr = lane & 15, segn = lane >> 4;

    __shared__ __attribute__((aligned(16))) bf16 As[2 * 128 * 32];
    __shared__ __attribute__((aligned(16))) bf16 Bs[2 * 128 * 32];

    const int srow = tid >> 2;
    const int gseg = (tid & 3) ^ ((srow >> 1) & 3);
    const int ldsw = wid * 512;
    const size_t acol = (size_t)gseg * 8;

    int aoff[4], boff[4];
#pragma unroll
    for (int i = 0; i < 4; ++i) {
        int ra = wm + i * 16 + lr;
        aoff[i] = ra * 32 + ((((ra >> 1) & 3) ^ segn)) * 8;
        int rb = wn + i * 16 + lr;
        boff[i] = rb * 32 + ((((rb >> 1) & 3) ^ segn)) * 8;
    }

    f32x4 acc[4][4];
#pragma unroll
    for (int i = 0; i < 4; ++i)
#pragma unroll
        for (int j = 0; j < 4; ++j)
#pragma unroll
            for (int r = 0; r < 4; ++r) acc[i][j][r] = 0.f;

    const bf16* Abase = Hbuf + (size_t)(off + mt * 128) * FDIM;  // HROWS slack covers tail
    const bf16* Bbase = B2w + ((size_t)e * DDIM + (size_t)nt * 128) * FDIM;
    const int k0 = kslice * (FDIM / 2), k1 = k0 + FDIM / 2;

#define STAGE2(B, KK)                                                           \
    {                                                                           \
        size_t col_ = (size_t)(KK) + acol;                                      \
        async_copy16(Abase + (size_t)srow * FDIM + col_,                        \
                     As + (B) * 4096 + ldsw);                                   \
        async_copy16(Bbase + (size_t)srow * FDIM + col_,                        \
                     Bs + (B) * 4096 + ldsw);                                   \
        async_copy16(Abase + (size_t)(srow + 64) * FDIM + col_,                 \
                     As + (B) * 4096 + 2048 + ldsw);                            \
        async_copy16(Bbase + (size_t)(srow + 64) * FDIM + col_,                 \
                     Bs + (B) * 4096 + 2048 + ldsw);                            \
    }

#define COMP2(B)                                                                \
    {                                                                           \
        bf16x8 af[4];                                                           \
        _Pragma("unroll")                                                       \
        for (int i = 0; i < 4; ++i)                                             \
            af[i] = *(const bf16x8*)(As + (B) * 4096 + aoff[i]);                \
        _Pragma("unroll")                                                       \
        for (int j = 0; j < 4; ++j) {                                           \
            bf16x8 bj = *(const bf16x8*)(Bs + (B) * 4096 + boff[j]);            \
            _Pragma("unroll")                                                   \
            for (int i = 0; i < 4; ++i)                                         \
                acc[i][j] = __builtin_amdgcn_mfma_f32_16x16x32_bf16(            \
                    af[i], bj, acc[i][j], 0, 0, 0);                             \
        }                                                                       \
    }

    STAGE2(0, k0)
    __syncthreads();
    for (int kk = k0; kk < k1; kk += 64) {
        STAGE2(1, kk + 32)
        COMP2(0)
        __syncthreads();
        if (kk + 64 < k1) STAGE2(0, kk + 64)
        COMP2(1)
        __syncthreads();
    }
#undef STAGE2
#undef COMP2

    const int lcol = lane & 15, lrow0 = (lane >> 4) * 4;
    float* Oslice = ObufS + (size_t)kslice * NSLOT * DDIM;
#pragma unroll
    for (int i = 0; i < 4; ++i) {
#pragma unroll
        for (int r = 0; r < 4; ++r) {
            int p = mt * 128 + wm + i * 16 + lrow0 + r;
            if (p >= count) continue;
            float* orow = Oslice + (size_t)(off + p) * DDIM + nt * 128 + wn + lcol;
#pragma unroll
            for (int j = 0; j < 4; ++j) orow[j * 16] = acc[i][j][r];
        }
    }
}

// ------ combine: out[t] = sum over 2 slots x 2 kslices --------------------
__global__ __launch_bounds__(256) void k_combine(
    const float* __restrict__ ObufS, const int* __restrict__ inv,
    float* __restrict__ out)
{
    int i = blockIdx.x * 256 + threadIdx.x;   // T*D/4 float4 units
    int t = i >> 8, d4 = i & 255;             // D/4 = 256
    int s0 = inv[2 * t], s1 = inv[2 * t + 1];
    const float4* O = (const float4*)ObufS;
    float4 a = O[(size_t)s0 * 256 + d4];
    float4 b = O[(size_t)s1 * 256 + d4];
    float4 c = O[(size_t)(NSLOT + s0) * 256 + d4];
    float4 d = O[(size_t)(NSLOT + s1) * 256 + d4];
    float4 r;
    r.x = a.x + b.x + c.x + d.x;
    r.y = a.y + b.y + c.y + d.y;
    r.z = a.z + b.z + c.z + d.z;
    r.w = a.w + b.w + c.w + d.w;
    ((float4*)out)[i] = r;
}

extern "C" void kernel_launch(void* const* d_in, const int* in_sizes, int n_in,
                              void* d_out, int out_size, void* d_ws, size_t ws_size,
                              hipStream_t stream)
{
    const float* x  = (const float*)d_in[0];
    const float* gw = (const float*)d_in[1];
    const float* w1 = (const float*)d_in[2];
    const float* w3 = (const float*)d_in[3];
    const float* w2 = (const float*)d_in[4];
    float* out = (float*)d_out;

    char* ws = (char*)d_ws;
    size_t o = 0;
    auto alloc = [&](size_t bytes) {
        char* p = ws + o;
        o += (bytes + 255) & ~(size_t)255;
        return p;
    };
    const size_t wsz = (size_t)NEXP * DDIM * FDIM * sizeof(bf16);   // 64 MiB
    bf16*  w1t   = (bf16*)alloc(wsz);                        // later: w2t
    bf16*  w3t   = (bf16*)alloc(wsz);                        // later: ObufS (fp32, exactly 64 MiB)
    bf16*  Hbuf  = (bf16*)alloc((size_t)HROWS * FDIM * sizeof(bf16));
    bf16*  xb    = (bf16*)alloc((size_t)T_TOK * DDIM * sizeof(bf16));
    int*   topE  = (int*)alloc(T_TOK * 2 * sizeof(int));
    float* topW  = (float*)alloc(T_TOK * 2 * sizeof(float));
    int*   cnt   = (int*)alloc(NEXP * sizeof(int));
    int*   offs  = (int*)alloc(NEXP * sizeof(int));
    int*   fill  = (int*)alloc(NEXP * sizeof(int));
    int*   list  = (int*)alloc(NSLOT * sizeof(int));
    float* wlist = (float*)alloc(NSLOT * sizeof(float));
    int*   inv   = (int*)alloc(NSLOT * sizeof(int));
    bf16*  w2t   = w1t;                   // after gemm01, w1t region is free
    float* ObufS = (float*)w3t;           // after gemm01, w3t region is free (2*NSLOT*DDIM*4 = 64 MiB)

    hipMemsetAsync(out, 0, (size_t)out_size * sizeof(float), stream);
    hipMemsetAsync(cnt, 0, NEXP * sizeof(int), stream);

    float* out_rl = out + (size_t)T_TOK * DDIM;

    k_cast<<<T_TOK * DDIM / 4 / 256, 256, 0, stream>>>(x, xb, T_TOK * DDIM / 4);
    k_router<<<T_TOK / 4, 256, 0, stream>>>(x, gw, out_rl, topE, topW, cnt);
    k_scan<<<1, 64, 0, stream>>>(cnt, offs, fill);
    k_build<<<(T_TOK + 255) / 256, 256, 0, stream>>>(topE, topW, offs, fill, list, wlist, inv);

    k_tc64<<<dim3(FDIM / 64, DDIM / 64, NEXP), 256, 0, stream>>>(w1, w1t, DDIM, FDIM);
    k_tc64<<<dim3(FDIM / 64, DDIM / 64, NEXP), 256, 0, stream>>>(w3, w3t, DDIM, FDIM);

    k_gemm01<<<dim3(FDIM / 128, T_TOK / 128, NEXP), 256, 0, stream>>>(
        xb, w1t, w3t, Hbuf, cnt, offs, list, wlist);

    k_tc64<<<dim3(DDIM / 64, FDIM / 64, NEXP), 256, 0, stream>>>(w2, w2t, FDIM, DDIM);

    k_gemm2<<<dim3(DDIM / 128, T_TOK / 128, NEXP * 2), 256, 0, stream>>>(
        Hbuf, w2t, ObufS, cnt, offs);

    k_combine<<<T_TOK * DDIM / 4 / 256, 256, 0, stream>>>(ObufS, inv, out);
}

// Round 5
// 786.719 us; speedup vs baseline: 1.6280x; 1.4608x over previous
//
#include <hip/hip_runtime.h>
#include <hip/hip_bf16.h>

typedef __bf16 bf16;
typedef __bf16 bf16x4 __attribute__((ext_vector_type(4)));
typedef __bf16 bf16x8 __attribute__((ext_vector_type(8)));
typedef float f32x4 __attribute__((ext_vector_type(4)));

#define T_TOK 4096
#define DDIM 1024
#define FDIM 4096
#define NEXP 8
#define NSLOT (2 * T_TOK)          // 8192 expert-slots
#define HROWS (NSLOT + 128)        // slack for tail-tile overreads

// async global->LDS, 16B per lane; LDS dest must be wave-uniform base,
// data lands at base + lane*16 (m97/m104 semantics)
__device__ __forceinline__ void async_copy16(const void* g, void* l) {
    __builtin_amdgcn_global_load_lds(
        (const __attribute__((address_space(1))) void*)g,
        (__attribute__((address_space(3))) void*)l, 16, 0, 0);
}

// ---------------- router: logits, top-2, partials, fused x->bf16 cast -----
// NO contended global atomics: same-address device-scope atomics measured
// ~795 cyc/op serialized (339 us for 1024-deep chains). Per-block partials
// (plain stores) + k_rreduce tree instead.
__global__ __launch_bounds__(256) void k_router(
    const float* __restrict__ x, const float* __restrict__ gw,
    bf16* __restrict__ xb,
    int* __restrict__ topE, float* __restrict__ topW,
    float* __restrict__ rlp, int* __restrict__ cntp)
{
    __shared__ float smrl[4][NEXP];
    __shared__ int lhist[NEXP];
    const int tid = threadIdx.x;
    const int wid = tid >> 6, lane = tid & 63;
    if (tid < NEXP) lhist[tid] = 0;
    __syncthreads();

    const int t = blockIdx.x * 4 + wid;
    const float4* xr = (const float4*)(x + (size_t)t * DDIM);
    bf16x4* xw = (bf16x4*)(xb + (size_t)t * DDIM);
    const float4* gr = (const float4*)gw;
    float acc[NEXP];
#pragma unroll
    for (int e = 0; e < NEXP; ++e) acc[e] = 0.f;
#pragma unroll
    for (int i = 0; i < 4; ++i) {
        float4 xv = xr[lane + 64 * i];
        bf16x4 o;
        o[0] = (bf16)xv.x; o[1] = (bf16)xv.y; o[2] = (bf16)xv.z; o[3] = (bf16)xv.w;
        xw[lane + 64 * i] = o;                 // fused cast (replaces k_cast)
#pragma unroll
        for (int e = 0; e < NEXP; ++e) {
            float4 gv = gr[e * 256 + lane + 64 * i];
            acc[e] += xv.x * gv.x + xv.y * gv.y + xv.z * gv.z + xv.w * gv.w;
        }
    }
#pragma unroll
    for (int e = 0; e < NEXP; ++e) {
#pragma unroll
        for (int s = 32; s > 0; s >>= 1) acc[e] += __shfl_down(acc[e], s, 64);
    }
    if (lane == 0) {
        float mx = acc[0];
#pragma unroll
        for (int e = 1; e < NEXP; ++e) mx = fmaxf(mx, acc[e]);
        float p[NEXP];
#pragma unroll
        for (int e = 0; e < NEXP; ++e) p[e] = __expf(acc[e] - mx);
        int e0 = 0;
#pragma unroll
        for (int e = 1; e < NEXP; ++e) if (p[e] > p[e0]) e0 = e;
        int e1 = (e0 == 0) ? 1 : 0;
#pragma unroll
        for (int e = 0; e < NEXP; ++e) if (e != e0 && p[e] > p[e1]) e1 = e;
        float s = p[e0] + p[e1];
        topE[2 * t] = e0; topE[2 * t + 1] = e1;
        topW[2 * t] = p[e0] / s; topW[2 * t + 1] = p[e1] / s;
#pragma unroll
        for (int e = 0; e < NEXP; ++e) smrl[wid][e] = acc[e];
        atomicAdd(&lhist[e0], 1);              // LDS atomics: cheap
        atomicAdd(&lhist[e1], 1);
    }
    __syncthreads();
    if (tid < NEXP) {
        rlp[(size_t)blockIdx.x * NEXP + tid] =
            smrl[0][tid] + smrl[1][tid] + smrl[2][tid] + smrl[3][tid];
        cntp[(size_t)blockIdx.x * NEXP + tid] = lhist[tid];
    }
}

// ---------------- reduce partials: out_rl (32 vals) + cnt[8] --------------
// blocks 0..31: (b,e) rl sums over 256 per-batch blocks; 32..39: cnt[e]
__global__ __launch_bounds__(256) void k_rreduce(
    const float* __restrict__ rlp, const int* __restrict__ cntp,
    float* __restrict__ out_rl, int* __restrict__ cnt)
{
    const int tid = threadIdx.x, lane = tid & 63, wid = tid >> 6;
    const int blk = blockIdx.x;
    __shared__ float redf[4];
    __shared__ int redi[4];
    if (blk < 32) {
        int b = blk >> 3, e = blk & 7;
        float v = rlp[(size_t)(b * 256 + tid) * NEXP + e];
#pragma unroll
        for (int s = 32; s > 0; s >>= 1) v += __shfl_down(v, s, 64);
        if (lane == 0) redf[wid] = v;
        __syncthreads();
        if (tid == 0)
            out_rl[b * NEXP + e] =
                (redf[0] + redf[1] + redf[2] + redf[3]) * (1.f / 1024.f);
    } else {
        int e = blk - 32;
        int v = 0;
#pragma unroll
        for (int k = 0; k < 4; ++k)
            v += cntp[(size_t)(tid + 256 * k) * NEXP + e];
#pragma unroll
        for (int s = 32; s > 0; s >>= 1) v += __shfl_down(v, s, 64);
        if (lane == 0) redi[wid] = v;
        __syncthreads();
        if (tid == 0) cnt[e] = redi[0] + redi[1] + redi[2] + redi[3];
    }
}

// ---------------- tiny exclusive scan over 8 experts ----------------------
__global__ void k_scan(const int* __restrict__ cnt, int* __restrict__ offs,
                       int* __restrict__ fill)
{
    if (threadIdx.x == 0) {
        int s = 0;
        for (int e = 0; e < NEXP; ++e) { offs[e] = s; s += cnt[e]; }
    }
    if (threadIdx.x < NEXP) fill[threadIdx.x] = 0;
}

// ---------------- build per-expert token lists + inverse ------------------
// hierarchical: LDS ranks + ONE global atomic per (block, expert)
// (was 8192 returning atomics over 8 addresses = ~1024-deep serial chains)
__global__ __launch_bounds__(256) void k_build(
    const int* __restrict__ topE, const float* __restrict__ topW,
    const int* __restrict__ offs, int* __restrict__ fill,
    int* __restrict__ list, float* __restrict__ wlist, int* __restrict__ inv)
{
    __shared__ int lfill[NEXP], gbase[NEXP];
    const int tid = threadIdx.x;
    if (tid < NEXP) lfill[tid] = 0;
    __syncthreads();
    const int t = blockIdx.x * 256 + tid;
    const int e0 = topE[2 * t], e1 = topE[2 * t + 1];
    const int r0 = atomicAdd(&lfill[e0], 1);   // LDS atomics
    const int r1 = atomicAdd(&lfill[e1], 1);
    __syncthreads();
    if (tid < NEXP) gbase[tid] = atomicAdd(&fill[tid], lfill[tid]);  // 8/block
    __syncthreads();
    const int s0 = offs[e0] + gbase[e0] + r0;
    const int s1 = offs[e1] + gbase[e1] + r1;
    list[s0] = t; wlist[s0] = topW[2 * t];     inv[2 * t]     = s0;
    list[s1] = t; wlist[s1] = topW[2 * t + 1]; inv[2 * t + 1] = s1;
}

// ------ weight transpose+cast [E][R][C] fp32 -> [E][C][R] bf16, 64x64 -----
__global__ __launch_bounds__(256) void k_tc64(
    const float* __restrict__ in, bf16* __restrict__ out, int R, int C)
{
    __shared__ float tile[64][72];
    int e = blockIdx.z;
    const float* I = in + (size_t)e * R * C;
    bf16* O = out + (size_t)e * R * C;
    int c0 = blockIdx.x * 64, r0 = blockIdx.y * 64;
    int tid = threadIdx.x;
#pragma unroll
    for (int it = 0; it < 4; ++it) {
        int idx = it * 256 + tid;              // 1024 float4 slots
        int row = idx >> 4, c4 = idx & 15;
        float4 v = *(const float4*)(I + (size_t)(r0 + row) * C + c0 + c4 * 4);
        tile[row][c4 * 4 + 0] = v.x; tile[row][c4 * 4 + 1] = v.y;
        tile[row][c4 * 4 + 2] = v.z; tile[row][c4 * 4 + 3] = v.w;
    }
    __syncthreads();
#pragma unroll
    for (int it = 0; it < 4; ++it) {
        int idx = it * 256 + tid;
        int c = idx >> 4, r4 = idx & 15;
        bf16x4 o;
#pragma unroll
        for (int j = 0; j < 4; ++j) o[j] = (bf16)tile[r4 * 4 + j][c];
        *(bf16x4*)(O + (size_t)(c0 + c) * R + r0 + r4 * 4) = o;
    }
}

// ------ fused GEMM1: H = silu(Xg@w1t) * (Xg@w3t) * w_slot -----------------
// 128x128x32 tile, double-buffered async staging, __launch_bounds__(256,2)
// for 2 blocks/CU (dual accumulators otherwise push total regs > 256).
__global__ __launch_bounds__(256, 2) void k_gemm01(
    const bf16* __restrict__ xb, const bf16* __restrict__ B1w,
    const bf16* __restrict__ B3w, bf16* __restrict__ Hbuf,
    const int* __restrict__ cnt, const int* __restrict__ offs,
    const int* __restrict__ list, const float* __restrict__ wlist)
{
    const int e = blockIdx.z, mt = blockIdx.y, nt = blockIdx.x;
    const int count = cnt[e];
    if (mt * 128 >= count) return;
    const int off = offs[e];
    const int tid = threadIdx.x;
    const int lane = tid & 63;
    const int wid = tid >> 6;
    const int wm = (wid >> 1) * 64, wn = (wid & 1) * 64;
    const int lr = lane & 15, segn = lane >> 4;

    __shared__ __attribute__((aligned(16))) bf16 As[2 * 128 * 32];
    __shared__ __attribute__((aligned(16))) bf16 B1s[2 * 128 * 32];
    __shared__ __attribute__((aligned(16))) bf16 B3s[2 * 128 * 32];
    __shared__ int tokbuf[128];

    if (tid < 128) {
        int p = mt * 128 + tid;
        int t = (p < count) ? list[off + p] : 0;   // clamp: garbage rows skipped in epilogue
        tokbuf[tid] = t;
    }
    __syncthreads();

    // staging geometry: lane data lands at LDS elems (B*4096 + it*2048 + tid*8)
    const int srow = tid >> 2;                      // + it*64
    const int gseg = (tid & 3) ^ ((srow >> 1) & 3); // same for it=0/1 (row+64 keeps (row>>1)&3)
    const int ldsw = wid * 512;                     // wave-uniform base (elems), + it*2048
    const size_t acol = (size_t)gseg * 8;

    // fragment LDS offsets (constant across k-steps)
    int aoff[4], boff[4];
#pragma unroll
    for (int i = 0; i < 4; ++i) {
        int ra = wm + i * 16 + lr;
        aoff[i] = ra * 32 + ((((ra >> 1) & 3) ^ segn)) * 8;
        int rb = wn + i * 16 + lr;
        boff[i] = rb * 32 + ((((rb >> 1) & 3) ^ segn)) * 8;
    }

    f32x4 acc1[4][4], acc3[4][4];
#pragma unroll
    for (int i = 0; i < 4; ++i)
#pragma unroll
        for (int j = 0; j < 4; ++j)
#pragma unroll
            for (int r = 0; r < 4; ++r) { acc1[i][j][r] = 0.f; acc3[i][j][r] = 0.f; }

    const bf16* B1base = B1w + ((size_t)e * FDIM + (size_t)nt * 128) * DDIM;
    const bf16* B3base = B3w + ((size_t)e * FDIM + (size_t)nt * 128) * DDIM;
    const int trow0 = tokbuf[srow], trow1 = tokbuf[srow + 64];

#define STAGE01(B, KK)                                                          \
    {                                                                           \
        size_t col_ = (size_t)(KK) + acol;                                      \
        async_copy16(xb + (size_t)trow0 * DDIM + col_,                          \
                     As + (B) * 4096 + ldsw);                                   \
        async_copy16(B1base + (size_t)srow * DDIM + col_,                       \
                     B1s + (B) * 4096 + ldsw);                                  \
        async_copy16(B3base + (size_t)srow * DDIM + col_,                       \
                     B3s + (B) * 4096 + ldsw);                                  \
        async_copy16(xb + (size_t)trow1 * DDIM + col_,                          \
                     As + (B) * 4096 + 2048 + ldsw);                            \
        async_copy16(B1base + (size_t)(srow + 64) * DDIM + col_,                \
                     B1s + (B) * 4096 + 2048 + ldsw);                           \
        async_copy16(B3base + (size_t)(srow + 64) * DDIM + col_,                \
                     B3s + (B) * 4096 + 2048 + ldsw);                           \
    }

// per-j B-fragment loads: only af[4] (16 regs) + b1j/b3j (8 regs) live,
// instead of 48 live fragment regs -> fits the (256,2) budget w/o spills
#define COMP01(B)                                                               \
    {                                                                           \
        bf16x8 af[4];                                                           \
        _Pragma("unroll")                                                       \
        for (int i = 0; i < 4; ++i)                                             \
            af[i] = *(const bf16x8*)(As + (B) * 4096 + aoff[i]);                \
        _Pragma("unroll")                                                       \
        for (int j = 0; j < 4; ++j) {                                           \
            bf16x8 b1j = *(const bf16x8*)(B1s + (B) * 4096 + boff[j]);          \
            bf16x8 b3j = *(const bf16x8*)(B3s + (B) * 4096 + boff[j]);          \
            _Pragma("unroll")                                                   \
            for (int i = 0; i < 4; ++i) {                                       \
                acc1[i][j] = __builtin_amdgcn_mfma_f32_16x16x32_bf16(           \
                    af[i], b1j, acc1[i][j], 0, 0, 0);                           \
                acc3[i][j] = __builtin_amdgcn_mfma_f32_16x16x32_bf16(           \
                    af[i], b3j, acc3[i][j], 0, 0, 0);                           \
            }                                                                   \
        }                                                                       \
    }

    STAGE01(0, 0)
    __syncthreads();                     // vmcnt(0) drain: tile 0 resident
    for (int kk = 0; kk < DDIM; kk += 64) {
        STAGE01(1, kk + 32)              // prefetch next tile (in flight under MFMA)
        COMP01(0)
        __syncthreads();                 // drain lands AFTER compute
        if (kk + 64 < DDIM) STAGE01(0, kk + 64)
        COMP01(1)
        __syncthreads();
    }
#undef STAGE01
#undef COMP01

    // C/D layout: col = lane&15, row = (lane>>4)*4 + reg
    const int lcol = lane & 15, lrow0 = (lane >> 4) * 4;
#pragma unroll
    for (int i = 0; i < 4; ++i) {
#pragma unroll
        for (int r = 0; r < 4; ++r) {
            int p = mt * 128 + wm + i * 16 + lrow0 + r;
            if (p >= count) continue;
            int slot = off + p;
            float wl = wlist[slot];
#pragma unroll
            for (int j = 0; j < 4; ++j) {
                int n = nt * 128 + wn + j * 16 + lcol;
                float a = acc1[i][j][r];
                float sv = a / (1.f + __expf(-a));
                Hbuf[(size_t)slot * FDIM + n] = (bf16)(sv * acc3[i][j][r] * wl);
            }
        }
    }
}

// ------ GEMM2: ObufS[kslice][slot] = H @ w2t (split-K=2, no atomics) ------
// same double-buffered prefetch structure as k_gemm01
__global__ __launch_bounds__(256, 2) void k_gemm2(
    const bf16* __restrict__ Hbuf, const bf16* __restrict__ B2w,
    float* __restrict__ ObufS,
    const int* __restrict__ cnt, const int* __restrict__ offs)
{
    const int kslice = blockIdx.z >> 3, e = blockIdx.z & 7;
    const int mt = blockIdx.y, nt = blockIdx.x;
    const int count = cnt[e];
    if (mt * 128 >= count) return;
    const int off = offs[e];
    const int tid = threadIdx.x;
    const int lane = tid & 63;
    const int wid = tid >> 6;
    const int wm = (wid >> 1) * 64, wn = (wid & 1) * 64;
    const int lr = lane & 15, segn = lane >> 4;

    __shared__ __attribute__((aligned(16))) bf16 As[2 * 128 * 32];
    __shared__ __attribute__((aligned(16))) bf16 Bs[2 * 128 * 32];

    const int srow = tid >> 2;
    const int gseg = (tid & 3) ^ ((srow >> 1) & 3);
    const int ldsw = wid * 512;
    const size_t acol = (size_t)gseg * 8;

    int aoff[4], boff[4];
#pragma unroll
    for (int i = 0; i < 4; ++i) {
        int ra = wm + i * 16 + lr;
        aoff[i] = ra * 32 + ((((ra >> 1) & 3) ^ segn)) * 8;
        int rb = wn + i * 16 + lr;
        boff[i] = rb * 32 + ((((rb >> 1) & 3) ^ segn)) * 8;
    }

    f32x4 acc[4][4];
#pragma unroll
    for (int i = 0; i < 4; ++i)
#pragma unroll
        for (int j = 0; j < 4; ++j)
#pragma unroll
            for (int r = 0; r < 4; ++r) acc[i][j][r] = 0.f;

    const bf16* Abase = Hbuf + (size_t)(off + mt * 128) * FDIM;  // HROWS slack covers tail
    const bf16* Bbase = B2w + ((size_t)e * DDIM + (size_t)nt * 128) * FDIM;
    const int k0 = kslice * (FDIM / 2), k1 = k0 + FDIM / 2;

#define STAGE2(B, KK)                                                           \
    {                                                                           \
        size_t col_ = (size_t)(KK) + acol;                                      \
        async_copy16(Abase + (size_t)srow * FDIM + col_,                        \
                     As + (B) * 4096 + ldsw);                                   \
        async_copy16(Bbase + (size_t)srow * FDIM + col_,                        \
                     Bs + (B) * 4096 + ldsw);                                   \
        async_copy16(Abase + (size_t)(srow + 64) * FDIM + col_,                 \
                     As + (B) * 4096 + 2048 + ldsw);                            \
        async_copy16(Bbase + (size_t)(srow + 64) * FDIM + col_,                 \
                     Bs + (B) * 4096 + 2048 + ldsw);                            \
    }

#define COMP2(B)                                                                \
    {                                                                           \
        bf16x8 af[4];                                                           \
        _Pragma("unroll")                                                       \
        for (int i = 0; i < 4; ++i)                                             \
            af[i] = *(const bf16x8*)(As + (B) * 4096 + aoff[i]);                \
        _Pragma("unroll")                                                       \
        for (int j = 0; j < 4; ++j) {                                           \
            bf16x8 bj = *(const bf16x8*)(Bs + (B) * 4096 + boff[j]);            \
            _Pragma("unroll")                                                   \
            for (int i = 0; i < 4; ++i)                                         \
                acc[i][j] = __builtin_amdgcn_mfma_f32_16x16x32_bf16(            \
                    af[i], bj, acc[i][j], 0, 0, 0);                             \
        }                                                                       \
    }

    STAGE2(0, k0)
    __syncthreads();
    for (int kk = k0; kk < k1; kk += 64) {
        STAGE2(1, kk + 32)
        COMP2(0)
        __syncthreads();
        if (kk + 64 < k1) STAGE2(0, kk + 64)
        COMP2(1)
        __syncthreads();
    }
#undef STAGE2
#undef COMP2

    const int lcol = lane & 15, lrow0 = (lane >> 4) * 4;
    float* Oslice = ObufS + (size_t)kslice * NSLOT * DDIM;
#pragma unroll
    for (int i = 0; i < 4; ++i) {
#pragma unroll
        for (int r = 0; r < 4; ++r) {
            int p = mt * 128 + wm + i * 16 + lrow0 + r;
            if (p >= count) continue;
            float* orow = Oslice + (size_t)(off + p) * DDIM + nt * 128 + wn + lcol;
#pragma unroll
            for (int j = 0; j < 4; ++j) orow[j * 16] = acc[i][j][r];
        }
    }
}

// ------ combine: out[t] = sum over 2 slots x 2 kslices --------------------
__global__ __launch_bounds__(256) void k_combine(
    const float* __restrict__ ObufS, const int* __restrict__ inv,
    float* __restrict__ out)
{
    int i = blockIdx.x * 256 + threadIdx.x;   // T*D/4 float4 units
    int t = i >> 8, d4 = i & 255;             // D/4 = 256
    int s0 = inv[2 * t], s1 = inv[2 * t + 1];
    const float4* O = (const float4*)ObufS;
    float4 a = O[(size_t)s0 * 256 + d4];
    float4 b = O[(size_t)s1 * 256 + d4];
    float4 c = O[(size_t)(NSLOT + s0) * 256 + d4];
    float4 d = O[(size_t)(NSLOT + s1) * 256 + d4];
    float4 r;
    r.x = a.x + b.x + c.x + d.x;
    r.y = a.y + b.y + c.y + d.y;
    r.z = a.z + b.z + c.z + d.z;
    r.w = a.w + b.w + c.w + d.w;
    ((float4*)out)[i] = r;
}

extern "C" void kernel_launch(void* const* d_in, const int* in_sizes, int n_in,
                              void* d_out, int out_size, void* d_ws, size_t ws_size,
                              hipStream_t stream)
{
    const float* x  = (const float*)d_in[0];
    const float* gw = (const float*)d_in[1];
    const float* w1 = (const float*)d_in[2];
    const float* w3 = (const float*)d_in[3];
    const float* w2 = (const float*)d_in[4];
    float* out = (float*)d_out;

    char* ws = (char*)d_ws;
    size_t o = 0;
    auto alloc = [&](size_t bytes) {
        char* p = ws + o;
        o += (bytes + 255) & ~(size_t)255;
        return p;
    };
    const size_t wsz = (size_t)NEXP * DDIM * FDIM * sizeof(bf16);   // 64 MiB
    bf16*  w1t   = (bf16*)alloc(wsz);                        // later: w2t
    bf16*  w3t   = (bf16*)alloc(wsz);                        // later: ObufS (fp32, exactly 64 MiB)
    bf16*  Hbuf  = (bf16*)alloc((size_t)HROWS * FDIM * sizeof(bf16));
    bf16*  xb    = (bf16*)alloc((size_t)T_TOK * DDIM * sizeof(bf16));
    int*   topE  = (int*)alloc(T_TOK * 2 * sizeof(int));
    float* topW  = (float*)alloc(T_TOK * 2 * sizeof(float));
    int*   cnt   = (int*)alloc(NEXP * sizeof(int));
    int*   offs  = (int*)alloc(NEXP * sizeof(int));
    int*   fill  = (int*)alloc(NEXP * sizeof(int));
    int*   list  = (int*)alloc(NSLOT * sizeof(int));
    float* wlist = (float*)alloc(NSLOT * sizeof(float));
    int*   inv   = (int*)alloc(NSLOT * sizeof(int));
    float* rlp   = (float*)alloc((size_t)(T_TOK / 4) * NEXP * sizeof(float));
    int*   cntp  = (int*)alloc((size_t)(T_TOK / 4) * NEXP * sizeof(int));
    bf16*  w2t   = w1t;                   // after gemm01, w1t region is free
    float* ObufS = (float*)w3t;           // after gemm01, w3t region is free (2*NSLOT*DDIM*4 = 64 MiB)

    hipMemsetAsync(out, 0, (size_t)out_size * sizeof(float), stream);

    float* out_rl = out + (size_t)T_TOK * DDIM;

    k_router<<<T_TOK / 4, 256, 0, stream>>>(x, gw, xb, topE, topW, rlp, cntp);
    k_rreduce<<<40, 256, 0, stream>>>(rlp, cntp, out_rl, cnt);
    k_scan<<<1, 64, 0, stream>>>(cnt, offs, fill);
    k_build<<<T_TOK / 256, 256, 0, stream>>>(topE, topW, offs, fill, list, wlist, inv);

    k_tc64<<<dim3(FDIM / 64, DDIM / 64, NEXP), 256, 0, stream>>>(w1, w1t, DDIM, FDIM);
    k_tc64<<<dim3(FDIM / 64, DDIM / 64, NEXP), 256, 0, stream>>>(w3, w3t, DDIM, FDIM);

    k_gemm01<<<dim3(FDIM / 128, T_TOK / 128, NEXP), 256, 0, stream>>>(
        xb, w1t, w3t, Hbuf, cnt, offs, list, wlist);

    k_tc64<<<dim3(DDIM / 64, FDIM / 64, NEXP), 256, 0, stream>>>(w2, w2t, FDIM, DDIM);

    k_gemm2<<<dim3(DDIM / 128, T_TOK / 128, NEXP * 2), 256, 0, stream>>>(
        Hbuf, w2t, ObufS, cnt, offs);

    k_combine<<<T_TOK * DDIM / 4 / 256, 256, 0, stream>>>(ObufS, inv, out);
}